// Round 7
// baseline (475.133 us; speedup 1.0000x reference)
//
#include <hip/hip_runtime.h>
#include <hip/hip_bf16.h>

#define N_NODES 8192
#define N_EDGES 262144
#define IN_DIM  512
#define HID     256
#define EMB     64
#define C2      128   // 2*EMB concat width

// ---------------- FUSED: edge-count (blocks 0..1023) + Wc GEMM (blocks 1024..1055) ----------------
__global__ __launch_bounds__(256) void k_count_wc(const int* __restrict__ dst, int* __restrict__ deg,
                                                  const float* __restrict__ W0, const float* __restrict__ Wm,
                                                  const float* __restrict__ Wl, float* __restrict__ WcT) {
    __shared__ float w0s[16][256];            // used by wc path only
    const int t = threadIdx.x;
    if (blockIdx.x < 1024) {                  // ---- count path ----
        int e = blockIdx.x * 256 + t;         // grid exactly covers E
        atomicAdd(&deg[dst[e]], 1);
        return;
    }
    // ---- Wc = W0 @ [Wm | Wl], stored transposed: WcT[j][k], j<128, k<512 ----
    const int kb = (blockIdx.x - 1024) * 16;
    #pragma unroll
    for (int m = 0; m < 4; ++m) {
        int f = t + 256 * m;                  // 0..1023 float4 slots (16*256/4)
        int row = f >> 6, q = f & 63;
        *(float4*)&w0s[row][q * 4] = *(const float4*)&W0[(size_t)(kb + row) * 256 + q * 4];
    }
    __syncthreads();
    const int j = t & 127, kh = t >> 7;       // col, k-half (8 rows each)
    const float* B = (j < 64) ? (Wm + j) : (Wl + (j - 64));   // wave-uniform branch
    float acc[8] = {};
    for (int h = 0; h < 256; h += 4) {
        float b0 = B[(h + 0) * 64], b1 = B[(h + 1) * 64];
        float b2 = B[(h + 2) * 64], b3 = B[(h + 3) * 64];
        #pragma unroll
        for (int r = 0; r < 8; ++r) {
            float4 x = *(const float4*)&w0s[kh * 8 + r][h];
            acc[r] += x.x * b0 + x.y * b1 + x.z * b2 + x.w * b3;
        }
    }
    #pragma unroll
    for (int r = 0; r < 8; ++r)
        WcT[(size_t)j * 512 + kb + kh * 8 + r] = acc[r];
}

// ---------------- FUSED: P = X @ Wc (blocks 0..255) + rowptr scan (block 256) ----------------
__global__ __launch_bounds__(256) void k_scan_gemm(const int* __restrict__ deg, int* __restrict__ rowptr,
                                                   const float* __restrict__ X, const float* __restrict__ WcT,
                                                   float* __restrict__ P) {
    const int t = threadIdx.x;
    if (blockIdx.x < 256) {                   // ---- gemm_p path ----
        __shared__ float Xs[32][68];          // 32 rows x 64-k chunk, padded
        const int i0 = blockIdx.x * 32;
        const int rg = t >> 6, cpair = t & 63, c0 = cpair * 2;
        float acc[8][2] = {};
        for (int kc = 0; kc < 512; kc += 64) {
            #pragma unroll
            for (int m = 0; m < 2; ++m) {
                int f = t + 256 * m;          // 0..511 float4 slots (32*64/4)
                int row = f >> 4, q = f & 15;
                *(float4*)&Xs[row][q * 4] = *(const float4*)&X[(size_t)(i0 + row) * 512 + kc + q * 4];
            }
            __syncthreads();
            #pragma unroll 4
            for (int k4 = 0; k4 < 16; ++k4) {
                float4 wA = *(const float4*)&WcT[(size_t)c0 * 512 + kc + k4 * 4];
                float4 wB = *(const float4*)&WcT[(size_t)(c0 + 1) * 512 + kc + k4 * 4];
                #pragma unroll
                for (int r = 0; r < 8; ++r) {
                    float4 x = *(const float4*)&Xs[rg * 8 + r][k4 * 4];
                    acc[r][0] += x.x * wA.x + x.y * wA.y + x.z * wA.z + x.w * wA.w;
                    acc[r][1] += x.x * wB.x + x.y * wB.y + x.z * wB.z + x.w * wB.w;
                }
            }
            __syncthreads();
        }
        #pragma unroll
        for (int r = 0; r < 8; ++r) {
            float2 v = make_float2(acc[r][0], acc[r][1]);
            *(float2*)&P[(size_t)(i0 + rg * 8 + r) * 128 + c0] = v;
        }
        return;
    }
    // ---- scan path: 256 threads x 32 elements ----
    __shared__ int part[256];
    const int base = t * 32;
    int incl[32];
    int s = 0;
    #pragma unroll
    for (int j4 = 0; j4 < 8; ++j4) {
        int4 d = *(const int4*)&deg[base + j4 * 4];
        s += d.x; incl[j4 * 4 + 0] = s;
        s += d.y; incl[j4 * 4 + 1] = s;
        s += d.z; incl[j4 * 4 + 2] = s;
        s += d.w; incl[j4 * 4 + 3] = s;
    }
    part[t] = s;
    __syncthreads();
    for (int off = 1; off < 256; off <<= 1) {
        int x = (t >= off) ? part[t - off] : 0;
        __syncthreads();
        part[t] += x;
        __syncthreads();
    }
    int excl = part[t] - s;
    if (t == 0) rowptr[0] = 0;
    #pragma unroll
    for (int j = 0; j < 32; ++j) rowptr[base + j + 1] = excl + incl[j];
}

__global__ __launch_bounds__(256) void k_fill(const int* __restrict__ src, const int* __restrict__ dst,
                                              const float* __restrict__ ew, const int* __restrict__ rowptr,
                                              int* __restrict__ cursor, int* __restrict__ srcs,
                                              float* __restrict__ wsorted) {
    int e = blockIdx.x * 256 + threadIdx.x;
    int d = dst[e];
    int p = rowptr[d] + atomicAdd(&cursor[d], 1);
    srcs[p] = src[e];
    wsorted[p] = ew[e];
}

// ---------------- aggregate: Out[d] = sum_{e: dst=d} In[src(e)] * w(e); optional Z epilogue ----------------
__global__ __launch_bounds__(128) void k_agg(const float* __restrict__ In, const int* __restrict__ rowptr,
                                             const int* __restrict__ srcs, const float* __restrict__ wsorted,
                                             float* __restrict__ Out, const float* __restrict__ noise,
                                             float* __restrict__ Z, int zpass) {
    const int b = blockIdx.x, t = threadIdx.x;
    const int beg = rowptr[b], end = rowptr[b + 1];
    float a0 = 0.f, a1 = 0.f, a2 = 0.f, a3 = 0.f;
    int i = beg;
    for (; i + 4 <= end; i += 4) {
        int   s0 = srcs[i],     s1 = srcs[i + 1], s2 = srcs[i + 2], s3 = srcs[i + 3];
        float w0 = wsorted[i],  w1 = wsorted[i + 1], w2 = wsorted[i + 2], w3 = wsorted[i + 3];
        a0 += In[(size_t)s0 * C2 + t] * w0;
        a1 += In[(size_t)s1 * C2 + t] * w1;
        a2 += In[(size_t)s2 * C2 + t] * w2;
        a3 += In[(size_t)s3 * C2 + t] * w3;
    }
    for (; i < end; ++i)
        a0 += In[(size_t)srcs[i] * C2 + t] * wsorted[i];
    float acc = (a0 + a1) + (a2 + a3);
    if (!zpass) {
        Out[(size_t)b * C2 + t] = acc;
    } else {
        __shared__ float u[C2];
        u[t] = acc;
        __syncthreads();
        if (t < 64) {
            float m = fmaxf(u[t], 0.f);
            float l = fmaxf(u[t + 64], 0.f);
            // clamp so Z is finite and a 64-term dot cannot exceed FLT_MAX:
            // |z| <= 1e18 -> |dot| <= 64 * 1e36 = 6.4e37 < 3.4e38
            float z = noise[(size_t)b * 64 + t] * expf(fminf(l, 80.f)) + m;
            z = fminf(fmaxf(z, -1e18f), 1e18f);
            Z[(size_t)b * 64 + t] = z;
        }
    }
}

// ---------------- out = Z @ Z^T, symmetric, 128x128 tiles, 8x8 acc ----------------
// k-loop = R4-proven feed: A from global (ty-broadcast), B in LDS (k-swizzled, conflict-free).
// mirror = R1-proven pattern scaled up: LDS-staged transpose in two 64-col halves (reuses the
// B-slab; stride 132 keeps float4 alignment + full bank coverage), then fully-coalesced
// 512B-row global writes. Replaces R4's 16-line splintered register-direct mirror (-~50us).
__global__ __launch_bounds__(256) void k_zzt(const float* __restrict__ Z, float* __restrict__ out) {
    if (blockIdx.x < blockIdx.y) return;      // upper triangle of 128x128 tiles: j0 >= i0
    __shared__ float S[8448];                 // 33.8 KB: B-slab [128][64] during k-loop; mirror half [64][132] after
    const int t = threadIdx.x;
    const int tx = t & 15, ty = t >> 4;
    const int i0 = blockIdx.y * 128, j0 = blockIdx.x * 128;
    // stage B rows j0..j0+127 (k-swizzled store: 2-way banks, free)
    #pragma unroll
    for (int m = 0; m < 8; ++m) {
        int f = t + 256 * m;                  // 0..2047 float4 slots (128 rows x 16)
        int row = f >> 4, q = f & 15;
        float4 v = *(const float4*)&Z[(size_t)(j0 + row) * 64 + q * 4];
        *(float4*)&S[row * 64 + ((q * 4) ^ ((row >> 3 & 7) << 2))] = v;
    }
    const float* A0 = Z + (size_t)(i0 + ty * 4) * 64;        // rows i0 + ty*4 + r
    const float* A1 = Z + (size_t)(i0 + 64 + ty * 4) * 64;   // rows i0 + 64 + ty*4 + r
    const int rb0 = tx * 4, rb1 = 64 + tx * 4;               // B rows owned by this thread
    const int swz = ((tx >> 1) & 7) << 2;                    // read-side swizzle (lane-const)
    __syncthreads();
    float acc[2][4][2][4] = {};
    for (int k = 0; k < 64; k += 4) {
        const int ks = k ^ swz;
        float4 a[2][4], b[2][4];
        #pragma unroll
        for (int r = 0; r < 4; ++r) {
            a[0][r] = *(const float4*)&A0[r * 64 + k];
            a[1][r] = *(const float4*)&A1[r * 64 + k];
            b[0][r] = *(const float4*)&S[(rb0 + r) * 64 + ks];
            b[1][r] = *(const float4*)&S[(rb1 + r) * 64 + ks];
        }
        #pragma unroll
        for (int rg = 0; rg < 2; ++rg)
            #pragma unroll
            for (int r = 0; r < 4; ++r)
                #pragma unroll
                for (int cg = 0; cg < 2; ++cg)
                    #pragma unroll
                    for (int c = 0; c < 4; ++c)
                        acc[rg][r][cg][c] += a[rg][r].x * b[cg][c].x + a[rg][r].y * b[cg][c].y
                                           + a[rg][r].z * b[cg][c].z + a[rg][r].w * b[cg][c].w;
    }
    // direct tile (i0, j0): per instr, 4 rows x 256B-contiguous segments (R4-proven)
    #pragma unroll
    for (int rg = 0; rg < 2; ++rg)
        #pragma unroll
        for (int r = 0; r < 4; ++r) {
            size_t row = (size_t)(i0 + rg * 64 + ty * 4 + r);
            #pragma unroll
            for (int cg = 0; cg < 2; ++cg) {
                float4 v = make_float4(acc[rg][r][cg][0], acc[rg][r][cg][1],
                                       acc[rg][r][cg][2], acc[rg][r][cg][3]);
                *(float4*)&out[row * N_NODES + j0 + cg * 64 + tx * 4] = v;
            }
        }
    // mirrored tile (j0, i0): two 64-col halves via LDS transpose, coalesced 512B-row writes
    if (i0 != j0) {
        #pragma unroll
        for (int cg = 0; cg < 2; ++cg) {
            __syncthreads();                  // S free (k-loop done / previous half read out)
            // transpose-in: M[col][irow], col = tx*4+c (0..63), irow = rg*64+ty*4+r; b128 over r
            #pragma unroll
            for (int c = 0; c < 4; ++c) {
                int col = tx * 4 + c;
                #pragma unroll
                for (int rg = 0; rg < 2; ++rg) {
                    float4 v = make_float4(acc[rg][0][cg][c], acc[rg][1][cg][c],
                                           acc[rg][2][cg][c], acc[rg][3][cg][c]);
                    *(float4*)&S[col * 132 + rg * 64 + ty * 4] = v;
                }
            }
            __syncthreads();
            // readout: 64 mirror-rows x 128 floats, fully coalesced
            #pragma unroll
            for (int m = 0; m < 8; ++m) {
                int f = t + 256 * m;          // 0..2047 float4 slots (64 rows x 32)
                int row = f >> 5, q = f & 31;
                float4 v = *(const float4*)&S[row * 132 + q * 4];
                *(float4*)&out[(size_t)(j0 + cg * 64 + row) * N_NODES + i0 + q * 4] = v;
            }
        }
    }
}

extern "C" void kernel_launch(void* const* d_in, const int* in_sizes, int n_in,
                              void* d_out, int out_size, void* d_ws, size_t ws_size,
                              hipStream_t stream) {
    const float* X     = (const float*)d_in[0];
    const int*   ei    = (const int*)d_in[1];
    const float* ew    = (const float*)d_in[2];
    const float* W0    = (const float*)d_in[3];
    const float* Wm    = (const float*)d_in[4];
    const float* Wl    = (const float*)d_in[5];
    const float* noise = (const float*)d_in[6];
    float* out = (float*)d_out;

    const int* srcI = ei;                 // edge_index[0]
    const int* dstI = ei + N_EDGES;       // edge_index[1]

    // workspace layout, all in d_ws (~12.9 MB)
    int*   deg     = (int*)d_ws;                          // 8192
    int*   cursor  = deg + 8192;                          // 8192
    int*   rowptr  = deg + 16384;                         // 8193 (pad to 24592)
    int*   srcs    = deg + 24592;                         // E
    float* wsorted = (float*)(deg + 24592 + N_EDGES);     // E
    float* WcT     = wsorted + N_EDGES;                   // 128*512
    float* P       = WcT + 128 * 512;                     // 8192*128
    float* U1      = P + (size_t)N_NODES * C2;            // 8192*128
    float* Z       = U1 + (size_t)N_NODES * C2;           // 8192*64

    hipMemsetAsync(deg, 0, 16384 * sizeof(int), stream);  // deg + cursor

    k_count_wc<<<1024 + 32, 256, 0, stream>>>(dstI, deg, W0, Wm, Wl, WcT);
    k_scan_gemm<<<256 + 1, 256, 0, stream>>>(deg, rowptr, X, WcT, P);
    k_fill<<<N_EDGES / 256, 256, 0, stream>>>(srcI, dstI, ew, rowptr, cursor, srcs, wsorted);
    k_agg<<<N_NODES, 128, 0, stream>>>(P, rowptr, srcs, wsorted, U1, nullptr, nullptr, 0);
    k_agg<<<N_NODES, 128, 0, stream>>>(U1, rowptr, srcs, wsorted, nullptr, noise, Z, 1);
    k_zzt<<<dim3(N_NODES / 128, N_NODES / 128), 256, 0, stream>>>(Z, out);
}

// Round 8
// 466.548 us; speedup vs baseline: 1.0184x; 1.0184x over previous
//
#include <hip/hip_runtime.h>
#include <hip/hip_bf16.h>

#define N_NODES 8192
#define N_EDGES 262144
#define IN_DIM  512
#define HID     256
#define EMB     64
#define C2      128   // 2*EMB concat width

// ---------------- FUSED: edge-count (blocks 0..1023) + Wc GEMM (blocks 1024..1055) ----------------
__global__ __launch_bounds__(256) void k_count_wc(const int* __restrict__ dst, int* __restrict__ deg,
                                                  const float* __restrict__ W0, const float* __restrict__ Wm,
                                                  const float* __restrict__ Wl, float* __restrict__ WcT) {
    __shared__ float w0s[16][256];            // used by wc path only
    const int t = threadIdx.x;
    if (blockIdx.x < 1024) {                  // ---- count path ----
        int e = blockIdx.x * 256 + t;         // grid exactly covers E
        atomicAdd(&deg[dst[e]], 1);
        return;
    }
    // ---- Wc = W0 @ [Wm | Wl], stored transposed: WcT[j][k], j<128, k<512 ----
    const int kb = (blockIdx.x - 1024) * 16;
    #pragma unroll
    for (int m = 0; m < 4; ++m) {
        int f = t + 256 * m;                  // 0..1023 float4 slots (16*256/4)
        int row = f >> 6, q = f & 63;
        *(float4*)&w0s[row][q * 4] = *(const float4*)&W0[(size_t)(kb + row) * 256 + q * 4];
    }
    __syncthreads();
    const int j = t & 127, kh = t >> 7;       // col, k-half (8 rows each)
    const float* B = (j < 64) ? (Wm + j) : (Wl + (j - 64));   // wave-uniform branch
    float acc[8] = {};
    for (int h = 0; h < 256; h += 4) {
        float b0 = B[(h + 0) * 64], b1 = B[(h + 1) * 64];
        float b2 = B[(h + 2) * 64], b3 = B[(h + 3) * 64];
        #pragma unroll
        for (int r = 0; r < 8; ++r) {
            float4 x = *(const float4*)&w0s[kh * 8 + r][h];
            acc[r] += x.x * b0 + x.y * b1 + x.z * b2 + x.w * b3;
        }
    }
    #pragma unroll
    for (int r = 0; r < 8; ++r)
        WcT[(size_t)j * 512 + kb + kh * 8 + r] = acc[r];
}

// ---------------- FUSED: P = X @ Wc (blocks 0..255) + rowptr scan (block 256) ----------------
__global__ __launch_bounds__(256) void k_scan_gemm(const int* __restrict__ deg, int* __restrict__ rowptr,
                                                   const float* __restrict__ X, const float* __restrict__ WcT,
                                                   float* __restrict__ P) {
    const int t = threadIdx.x;
    if (blockIdx.x < 256) {                   // ---- gemm_p path ----
        __shared__ float Xs[32][68];          // 32 rows x 64-k chunk, padded
        const int i0 = blockIdx.x * 32;
        const int rg = t >> 6, cpair = t & 63, c0 = cpair * 2;
        float acc[8][2] = {};
        for (int kc = 0; kc < 512; kc += 64) {
            #pragma unroll
            for (int m = 0; m < 2; ++m) {
                int f = t + 256 * m;          // 0..511 float4 slots (32*64/4)
                int row = f >> 4, q = f & 15;
                *(float4*)&Xs[row][q * 4] = *(const float4*)&X[(size_t)(i0 + row) * 512 + kc + q * 4];
            }
            __syncthreads();
            #pragma unroll 4
            for (int k4 = 0; k4 < 16; ++k4) {
                float4 wA = *(const float4*)&WcT[(size_t)c0 * 512 + kc + k4 * 4];
                float4 wB = *(const float4*)&WcT[(size_t)(c0 + 1) * 512 + kc + k4 * 4];
                #pragma unroll
                for (int r = 0; r < 8; ++r) {
                    float4 x = *(const float4*)&Xs[rg * 8 + r][k4 * 4];
                    acc[r][0] += x.x * wA.x + x.y * wA.y + x.z * wA.z + x.w * wA.w;
                    acc[r][1] += x.x * wB.x + x.y * wB.y + x.z * wB.z + x.w * wB.w;
                }
            }
            __syncthreads();
        }
        #pragma unroll
        for (int r = 0; r < 8; ++r) {
            float2 v = make_float2(acc[r][0], acc[r][1]);
            *(float2*)&P[(size_t)(i0 + rg * 8 + r) * 128 + c0] = v;
        }
        return;
    }
    // ---- scan path: 256 threads x 32 elements ----
    __shared__ int part[256];
    const int base = t * 32;
    int incl[32];
    int s = 0;
    #pragma unroll
    for (int j4 = 0; j4 < 8; ++j4) {
        int4 d = *(const int4*)&deg[base + j4 * 4];
        s += d.x; incl[j4 * 4 + 0] = s;
        s += d.y; incl[j4 * 4 + 1] = s;
        s += d.z; incl[j4 * 4 + 2] = s;
        s += d.w; incl[j4 * 4 + 3] = s;
    }
    part[t] = s;
    __syncthreads();
    for (int off = 1; off < 256; off <<= 1) {
        int x = (t >= off) ? part[t - off] : 0;
        __syncthreads();
        part[t] += x;
        __syncthreads();
    }
    int excl = part[t] - s;
    if (t == 0) rowptr[0] = 0;
    #pragma unroll
    for (int j = 0; j < 32; ++j) rowptr[base + j + 1] = excl + incl[j];
}

__global__ __launch_bounds__(256) void k_fill(const int* __restrict__ src, const int* __restrict__ dst,
                                              const float* __restrict__ ew, const int* __restrict__ rowptr,
                                              int* __restrict__ cursor, int* __restrict__ srcs,
                                              float* __restrict__ wsorted) {
    int e = blockIdx.x * 256 + threadIdx.x;
    int d = dst[e];
    int p = rowptr[d] + atomicAdd(&cursor[d], 1);
    srcs[p] = src[e];
    wsorted[p] = ew[e];
}

// ---------------- aggregate: Out[d] = sum_{e: dst=d} In[src(e)] * w(e); optional Z epilogue ----------------
__global__ __launch_bounds__(128) void k_agg(const float* __restrict__ In, const int* __restrict__ rowptr,
                                             const int* __restrict__ srcs, const float* __restrict__ wsorted,
                                             float* __restrict__ Out, const float* __restrict__ noise,
                                             float* __restrict__ Z, int zpass) {
    const int b = blockIdx.x, t = threadIdx.x;
    const int beg = rowptr[b], end = rowptr[b + 1];
    float a0 = 0.f, a1 = 0.f, a2 = 0.f, a3 = 0.f;
    int i = beg;
    for (; i + 4 <= end; i += 4) {
        int   s0 = srcs[i],     s1 = srcs[i + 1], s2 = srcs[i + 2], s3 = srcs[i + 3];
        float w0 = wsorted[i],  w1 = wsorted[i + 1], w2 = wsorted[i + 2], w3 = wsorted[i + 3];
        a0 += In[(size_t)s0 * C2 + t] * w0;
        a1 += In[(size_t)s1 * C2 + t] * w1;
        a2 += In[(size_t)s2 * C2 + t] * w2;
        a3 += In[(size_t)s3 * C2 + t] * w3;
    }
    for (; i < end; ++i)
        a0 += In[(size_t)srcs[i] * C2 + t] * wsorted[i];
    float acc = (a0 + a1) + (a2 + a3);
    if (!zpass) {
        Out[(size_t)b * C2 + t] = acc;
    } else {
        __shared__ float u[C2];
        u[t] = acc;
        __syncthreads();
        if (t < 64) {
            float m = fmaxf(u[t], 0.f);
            float l = fmaxf(u[t + 64], 0.f);
            // clamp so Z is finite and a 64-term dot cannot exceed FLT_MAX:
            // |z| <= 1e18 -> |dot| <= 64 * 1e36 = 6.4e37 < 3.4e38
            float z = noise[(size_t)b * 64 + t] * expf(fminf(l, 80.f)) + m;
            z = fminf(fmaxf(z, -1e18f), 1e18f);
            Z[(size_t)b * 64 + t] = z;
        }
    }
}

// ---------------- out = Z @ Z^T, symmetric, 64x64 tiles ----------------
// R1's proven 64² structure with the LDS traffic HALVED: A comes from global as row-major
// float4 k-chunks (ty-broadcast, R3/R4-proven access pattern), only B stays in LDS
// ([row][k] slab with the R4-proven k-XOR swizzle; 2-way banks on store and read).
// Inner loop: 4 LDS + 4 global b128 per 4-k chunk feed 64 FMA (1 LDS read/thread/k vs R1's 2).
// Mirror = R1's verbatim LDS transpose (slab reused, [64][68]).
__global__ __launch_bounds__(256) void k_zzt(const float* __restrict__ Z, float* __restrict__ out) {
    if (blockIdx.x < blockIdx.y) return;      // upper triangle of 64x64 tiles: j0 >= i0
    __shared__ float S[64 * 68];              // 17.4 KB: B-slab [64][64] (k-swizzled), then mirror [64][68]
    const int t = threadIdx.x;
    const int tx = t & 15, ty = t >> 4;
    const int i0 = blockIdx.y * 64, j0 = blockIdx.x * 64;
    // stage B rows j0..j0+63 (coalesced 256B rows; k-swizzled store -> 2-way banks)
    #pragma unroll
    for (int m = 0; m < 4; ++m) {
        int f = t + 256 * m;                  // 0..1023 float4 slots (64 rows x 16)
        int row = f >> 4, q = f & 15;
        float4 v = *(const float4*)&Z[(size_t)(j0 + row) * 64 + q * 4];
        *(float4*)&S[row * 64 + ((q * 4) ^ ((row >> 3 & 7) << 2))] = v;
    }
    const float* A0 = Z + (size_t)(i0 + ty * 4) * 64;   // thread's 4 A-rows (ty-broadcast in wave)
    const int rb = tx * 4;                              // thread's 4 B-rows
    const int swz = ((tx >> 1) & 7) << 2;               // (tx*4+r)>>3 == tx>>1 for r<4 -> uniform per thread
    __syncthreads();
    float acc[4][4] = {};
    for (int k = 0; k < 64; k += 4) {
        const int ks = k ^ swz;
        float4 a[4], b[4];
        #pragma unroll
        for (int r = 0; r < 4; ++r) {
            a[r] = *(const float4*)&A0[r * 64 + k];            // global: 4 distinct 16B addrs/wave
            b[r] = *(const float4*)&S[(rb + r) * 64 + ks];     // LDS: 2-way banks
        }
        #pragma unroll
        for (int r = 0; r < 4; ++r)
            #pragma unroll
            for (int c = 0; c < 4; ++c)
                acc[r][c] += a[r].x * b[c].x + a[r].y * b[c].y + a[r].z * b[c].z + a[r].w * b[c].w;
    }
    // direct tile (i0, j0) — coalesced float4 rows
    #pragma unroll
    for (int r = 0; r < 4; ++r) {
        float4 v = make_float4(acc[r][0], acc[r][1], acc[r][2], acc[r][3]);
        *(float4*)&out[(size_t)(i0 + ty * 4 + r) * N_NODES + j0 + tx * 4] = v;
    }
    // mirrored tile (j0, i0): R1-proven LDS transpose -> coalesced writes
    if (i0 != j0) {
        __syncthreads();                      // slab free after k-loop
        #pragma unroll
        for (int r = 0; r < 4; ++r)
            #pragma unroll
            for (int c = 0; c < 4; ++c)
                S[(tx * 4 + c) * 68 + ty * 4 + r] = acc[r][c];   // S[col][row] = tile^T
        __syncthreads();
        #pragma unroll
        for (int m = 0; m < 4; ++m) {
            int f = t + 256 * m;              // 0..1023 float4 slots
            int row = f >> 4, q = f & 15;
            float4 v = *(const float4*)&S[row * 68 + q * 4];
            *(float4*)&out[(size_t)(j0 + row) * N_NODES + i0 + q * 4] = v;
        }
    }
}

extern "C" void kernel_launch(void* const* d_in, const int* in_sizes, int n_in,
                              void* d_out, int out_size, void* d_ws, size_t ws_size,
                              hipStream_t stream) {
    const float* X     = (const float*)d_in[0];
    const int*   ei    = (const int*)d_in[1];
    const float* ew    = (const float*)d_in[2];
    const float* W0    = (const float*)d_in[3];
    const float* Wm    = (const float*)d_in[4];
    const float* Wl    = (const float*)d_in[5];
    const float* noise = (const float*)d_in[6];
    float* out = (float*)d_out;

    const int* srcI = ei;                 // edge_index[0]
    const int* dstI = ei + N_EDGES;       // edge_index[1]

    // workspace layout, all in d_ws (~12.9 MB)
    int*   deg     = (int*)d_ws;                          // 8192
    int*   cursor  = deg + 8192;                          // 8192
    int*   rowptr  = deg + 16384;                         // 8193 (pad to 24592)
    int*   srcs    = deg + 24592;                         // E
    float* wsorted = (float*)(deg + 24592 + N_EDGES);     // E
    float* WcT     = wsorted + N_EDGES;                   // 128*512
    float* P       = WcT + 128 * 512;                     // 8192*128
    float* U1      = P + (size_t)N_NODES * C2;            // 8192*128
    float* Z       = U1 + (size_t)N_NODES * C2;           // 8192*64

    hipMemsetAsync(deg, 0, 16384 * sizeof(int), stream);  // deg + cursor

    k_count_wc<<<1024 + 32, 256, 0, stream>>>(dstI, deg, W0, Wm, Wl, WcT);
    k_scan_gemm<<<256 + 1, 256, 0, stream>>>(deg, rowptr, X, WcT, P);
    k_fill<<<N_EDGES / 256, 256, 0, stream>>>(srcI, dstI, ew, rowptr, cursor, srcs, wsorted);
    k_agg<<<N_NODES, 128, 0, stream>>>(P, rowptr, srcs, wsorted, U1, nullptr, nullptr, 0);
    k_agg<<<N_NODES, 128, 0, stream>>>(U1, rowptr, srcs, wsorted, nullptr, noise, Z, 1);
    k_zzt<<<dim3(N_NODES / 64, N_NODES / 64), 256, 0, stream>>>(Z, out);
}